// Round 1
// baseline (2094.340 us; speedup 1.0000x reference)
//
#include <hip/hip_runtime.h>
#include <cstdint>
#include <cstddef>

#define FLT_MAX_ 3.402823466e+38f

// ---------- ordered-uint <-> float (for atomic min/max over floats) ----------
__device__ __forceinline__ unsigned f2o(float f) {
  unsigned b = __float_as_uint(f);
  return (b & 0x80000000u) ? ~b : (b | 0x80000000u);
}
__device__ __forceinline__ float o2f(unsigned u) {
  unsigned b = (u & 0x80000000u) ? (u & 0x7fffffffu) : ~u;
  return __uint_as_float(b);
}

// Scalar block S (u32 word indices in ws):
// 0..3 pcmin(ordered)  4 hmin(ordered)  5 hmax(ordered)
// 6..9 vcmin(int)      10..13 vcmax(int) 14..17 dims(int)
// 18..21 pcmin(float bits) 22 hmin(float bits) 23 hmax(float bits)

__global__ void init_scalars_k(unsigned* S) {
  if (threadIdx.x == 0) {
    S[0]=S[1]=S[2]=S[3]=0xFFFFFFFFu;
    S[4]=0xFFFFFFFFu;
    S[5]=0u;
    int* Si = (int*)S;
    Si[6]=Si[7]=Si[8]=Si[9]=0x7FFFFFFF;
    Si[10]=Si[11]=Si[12]=Si[13]=(int)0x80000000;
  }
}

__global__ __launch_bounds__(256) void reduce_stats_k(const float4* __restrict__ bxyz,
    const float* __restrict__ h, int N, unsigned* S) {
  float m0=FLT_MAX_, m1=FLT_MAX_, m2=FLT_MAX_, m3=FLT_MAX_;
  float hmn=FLT_MAX_, hmx=-FLT_MAX_;
  for (int i = blockIdx.x*blockDim.x + threadIdx.x; i < N; i += gridDim.x*blockDim.x) {
    float4 p = bxyz[i];
    m0 = fminf(m0, p.x); m1 = fminf(m1, p.y);
    m2 = fminf(m2, p.z); m3 = fminf(m3, p.w);
    float hv = h[i];
    hmn = fminf(hmn, hv); hmx = fmaxf(hmx, hv);
  }
  for (int o = 32; o >= 1; o >>= 1) {
    m0 = fminf(m0, __shfl_down(m0, o));
    m1 = fminf(m1, __shfl_down(m1, o));
    m2 = fminf(m2, __shfl_down(m2, o));
    m3 = fminf(m3, __shfl_down(m3, o));
    hmn = fminf(hmn, __shfl_down(hmn, o));
    hmx = fmaxf(hmx, __shfl_down(hmx, o));
  }
  if ((threadIdx.x & 63) == 0) {
    atomicMin(&S[0], f2o(m0)); atomicMin(&S[1], f2o(m1));
    atomicMin(&S[2], f2o(m2)); atomicMin(&S[3], f2o(m3));
    atomicMin(&S[4], f2o(hmn)); atomicMax(&S[5], f2o(hmx));
  }
}

__global__ void finalize1_k(unsigned* S) {
  if (threadIdx.x == 0) {
    S[18] = __float_as_uint(o2f(S[0]));
    S[19] = __float_as_uint(o2f(S[1]));
    S[20] = __float_as_uint(o2f(S[2]));
    S[21] = __float_as_uint(o2f(S[3]));
    S[22] = __float_as_uint(o2f(S[4]));
    S[23] = __float_as_uint(o2f(S[5]));
  }
}

__global__ __launch_bounds__(256) void vc_minmax_k(const float4* __restrict__ bxyz,
    const float* __restrict__ vs, unsigned* S, int N) {
  float pm0 = __uint_as_float(S[18]), pm1 = __uint_as_float(S[19]);
  float pm2 = __uint_as_float(S[20]), pm3 = __uint_as_float(S[21]);
  float v0 = vs[0], v1 = vs[1], v2 = vs[2], v3 = vs[3];
  int mn0=0x7FFFFFFF,mn1=0x7FFFFFFF,mn2=0x7FFFFFFF,mn3=0x7FFFFFFF;
  int mx0=(int)0x80000000,mx1=(int)0x80000000,mx2=(int)0x80000000,mx3=(int)0x80000000;
  for (int i = blockIdx.x*blockDim.x + threadIdx.x; i < N; i += gridDim.x*blockDim.x) {
    float4 p = bxyz[i];
    int c0 = (int)floorf(__fdiv_rn(__fsub_rn(p.x, pm0), v0));
    int c1 = (int)floorf(__fdiv_rn(__fsub_rn(p.y, pm1), v1));
    int c2 = (int)floorf(__fdiv_rn(__fsub_rn(p.z, pm2), v2));
    int c3 = (int)floorf(__fdiv_rn(__fsub_rn(p.w, pm3), v3));
    mn0 = min(mn0,c0); mx0 = max(mx0,c0);
    mn1 = min(mn1,c1); mx1 = max(mx1,c1);
    mn2 = min(mn2,c2); mx2 = max(mx2,c2);
    mn3 = min(mn3,c3); mx3 = max(mx3,c3);
  }
  for (int o = 32; o >= 1; o >>= 1) {
    mn0 = min(mn0, __shfl_down(mn0, o)); mx0 = max(mx0, __shfl_down(mx0, o));
    mn1 = min(mn1, __shfl_down(mn1, o)); mx1 = max(mx1, __shfl_down(mx1, o));
    mn2 = min(mn2, __shfl_down(mn2, o)); mx2 = max(mx2, __shfl_down(mx2, o));
    mn3 = min(mn3, __shfl_down(mn3, o)); mx3 = max(mx3, __shfl_down(mx3, o));
  }
  if ((threadIdx.x & 63) == 0) {
    int* Si = (int*)S;
    atomicMin(&Si[6], mn0); atomicMin(&Si[7], mn1);
    atomicMin(&Si[8], mn2); atomicMin(&Si[9], mn3);
    atomicMax(&Si[10], mx0); atomicMax(&Si[11], mx1);
    atomicMax(&Si[12], mx2); atomicMax(&Si[13], mx3);
  }
}

__global__ void finalize2_k(unsigned* S) {
  if (threadIdx.x == 0) {
    int* Si = (int*)S;
    for (int c = 0; c < 4; c++) Si[14+c] = Si[10+c] - Si[6+c] + 1;
  }
}

__global__ __launch_bounds__(256) void compute_codes_k(const float4* __restrict__ bxyz,
    const float* __restrict__ vs, const unsigned* __restrict__ S,
    unsigned* __restrict__ B, unsigned* __restrict__ Abits, float4* __restrict__ out9,
    int N, int NW) {
  int i = blockIdx.x*256 + threadIdx.x;
  if (i >= N) return;
  const int* Si = (const int*)S;
  float pm0 = __uint_as_float(S[18]), pm1 = __uint_as_float(S[19]);
  float pm2 = __uint_as_float(S[20]), pm3 = __uint_as_float(S[21]);
  float v0 = vs[0], v1 = vs[1], v2 = vs[2], v3 = vs[3];
  float4 p = bxyz[i];
  int c0 = (int)floorf(__fdiv_rn(__fsub_rn(p.x, pm0), v0)) - Si[6];
  int c1 = (int)floorf(__fdiv_rn(__fsub_rn(p.y, pm1), v1)) - Si[7];
  int c2 = (int)floorf(__fdiv_rn(__fsub_rn(p.z, pm2), v2)) - Si[8];
  int c3 = (int)floorf(__fdiv_rn(__fsub_rn(p.w, pm3), v3)) - Si[9];
  int d1 = Si[15], d2 = Si[16], d3 = Si[17];
  unsigned code = (unsigned)(((c0*d1 + c1)*d2 + c2)*d3 + c3);
  B[i] = code;
  unsigned wi = code >> 5;
  if ((int)wi < NW) atomicOr(&Abits[wi], 1u << (code & 31u));
  out9[i] = make_float4((float)c0, (float)c1, (float)c2, (float)c3);
}

__global__ __launch_bounds__(256) void popc_k(const unsigned* __restrict__ Abits,
    unsigned* __restrict__ P, int NW) {
  int i = blockIdx.x*256 + threadIdx.x;
  if (i < NW) P[i] = (unsigned)__popc(Abits[i]);
}

// ---------------- generic u32 exclusive scan (3-kernel) ----------------
__device__ __forceinline__ unsigned wave_incl_scan_u32(unsigned x) {
  int lane = threadIdx.x & 63;
  #pragma unroll
  for (int d = 1; d < 64; d <<= 1) {
    unsigned y = __shfl_up(x, d);
    if (lane >= d) x += y;
  }
  return x;
}

__device__ __forceinline__ unsigned block_excl_scan256(unsigned s, unsigned* lds5) {
  int lane = threadIdx.x & 63, w = threadIdx.x >> 6;
  unsigned incl = wave_incl_scan_u32(s);
  if (lane == 63) lds5[w] = incl;
  __syncthreads();
  if (threadIdx.x == 0) {
    unsigned run = 0;
    #pragma unroll
    for (int k = 0; k < 4; k++) { unsigned t = lds5[k]; lds5[k] = run; run += t; }
    lds5[4] = run;
  }
  __syncthreads();
  return lds5[w] + (incl - s);
}

__global__ __launch_bounds__(256) void scan_partials_k(const unsigned* __restrict__ src,
    unsigned* __restrict__ partial, long L) {
  __shared__ unsigned lds5[5];
  long base = (long)blockIdx.x*4096 + (long)threadIdx.x*16;
  unsigned s = 0;
  #pragma unroll
  for (int k = 0; k < 16; k++) { long i = base + k; if (i < L) s += src[i]; }
  block_excl_scan256(s, lds5);
  if (threadIdx.x == 0) partial[blockIdx.x] = lds5[4];
}

__global__ __launch_bounds__(256) void scan_single_k(unsigned* arr, int L) {
  __shared__ unsigned lds5[5];
  __shared__ unsigned carry_s;
  if (threadIdx.x == 0) carry_s = 0;
  __syncthreads();
  int tiles = (L + 4095) / 4096;
  for (int t = 0; t < tiles; t++) {
    long base = (long)t*4096 + (long)threadIdx.x*16;
    unsigned v[16], s = 0;
    #pragma unroll
    for (int k = 0; k < 16; k++) { long i = base + k; v[k] = (i < L) ? arr[i] : 0u; s += v[k]; }
    unsigned carry = carry_s;
    unsigned e = block_excl_scan256(s, lds5);
    unsigned run = carry + e;
    #pragma unroll
    for (int k = 0; k < 16; k++) { long i = base + k; if (i < L) arr[i] = run; run += v[k]; }
    __syncthreads();
    if (threadIdx.x == 0) carry_s = carry + lds5[4];
    __syncthreads();
  }
}

__global__ __launch_bounds__(256) void scan_apply_k(const unsigned* __restrict__ src,
    unsigned* __restrict__ dst, const unsigned* __restrict__ partial, long L) {
  __shared__ unsigned lds5[5];
  long base = (long)blockIdx.x*4096 + (long)threadIdx.x*16;
  unsigned v[16], s = 0;
  #pragma unroll
  for (int k = 0; k < 16; k++) { long i = base + k; v[k] = (i < L) ? src[i] : 0u; s += v[k]; }
  unsigned e = block_excl_scan256(s, lds5);
  unsigned run = partial[blockIdx.x] + e;
  #pragma unroll
  for (int k = 0; k < 16; k++) { long i = base + k; if (i < L) dst[i] = run; run += v[k]; }
}

// ---------------- per-point rank / tval / counts ----------------
__global__ __launch_bounds__(256) void point_rank_k(const unsigned* __restrict__ B,
    const unsigned* __restrict__ Abits, const unsigned* __restrict__ P,
    const float* __restrict__ h, const unsigned* __restrict__ S,
    float* __restrict__ out8, unsigned* __restrict__ D, unsigned* __restrict__ E,
    float* __restrict__ C, int N) {
  int i = blockIdx.x*256 + threadIdx.x;
  if (i >= N) return;
  unsigned code = B[i];
  unsigned wi = code >> 5, bi = code & 31u;
  unsigned idx = P[wi] + (unsigned)__popc(Abits[wi] & ((1u << bi) - 1u));
  out8[i] = (float)idx;
  D[i] = idx;
  atomicAdd(&E[idx], 1u);
  float hmin = __uint_as_float(S[22]);
  float hmax = __uint_as_float(S[23]);
  // EXACT replication of: (h - min_val) + voxel_index*max_val  (no FMA contraction)
  C[i] = __fadd_rn(__fsub_rn(h[i], hmin), __fmul_rn((float)idx, hmax));
}

__global__ __launch_bounds__(256) void build_plist_k(const unsigned* __restrict__ D,
    unsigned* __restrict__ F, unsigned* __restrict__ G, int N) {
  int i = blockIdx.x*256 + threadIdx.x;
  if (i >= N) return;
  unsigned idx = D[i];
  unsigned pos = atomicAdd(&F[idx], 1u);
  G[pos] = (unsigned)i;
}

// ---------------- stable LSD radix sort, 4 x 8-bit, keys-only ----------------
__global__ __launch_bounds__(64) void radix_hist_k(const unsigned* __restrict__ src,
    unsigned* __restrict__ ghist, int N, int shift) {
  __shared__ unsigned short hist[256][66];   // +2 pad breaks bank conflicts
  int tid = threadIdx.x;
  unsigned* hz = (unsigned*)&hist[0][0];
  for (int k = tid; k < 256*33; k += 64) hz[k] = 0u;
  __syncthreads();
  int base = blockIdx.x*4096 + tid*64;
  for (int e = 0; e < 64; e++) {
    int i = base + e;
    if (i < N) {
      unsigned d = (src[i] >> shift) & 255u;
      hist[d][tid]++;
    }
  }
  __syncthreads();
  int nb = gridDim.x;
  #pragma unroll
  for (int k = 0; k < 4; k++) {
    int d = tid*4 + k;
    unsigned s = 0;
    for (int t = 0; t < 64; t++) s += hist[d][t];
    ghist[d*nb + blockIdx.x] = s;
  }
}

__global__ __launch_bounds__(64) void radix_scatter_k(const unsigned* __restrict__ src,
    unsigned* __restrict__ dst, const unsigned* __restrict__ ghist, int N, int shift) {
  __shared__ unsigned short hist[256][66];
  __shared__ unsigned gbase[256];
  int tid = threadIdx.x;
  unsigned* hz = (unsigned*)&hist[0][0];
  for (int k = tid; k < 256*33; k += 64) hz[k] = 0u;
  __syncthreads();
  int base = blockIdx.x*4096 + tid*64;
  for (int e = 0; e < 64; e++) {
    int i = base + e;
    if (i < N) {
      unsigned d = (src[i] >> shift) & 255u;
      hist[d][tid]++;
    }
  }
  __syncthreads();
  int nb = gridDim.x;
  #pragma unroll
  for (int k = 0; k < 4; k++) {
    int d = tid*4 + k;
    unsigned run = 0;
    for (int t = 0; t < 64; t++) {
      unsigned tmp = hist[d][t];
      hist[d][t] = (unsigned short)run;
      run += tmp;
    }
    gbase[d] = ghist[d*nb + blockIdx.x];
  }
  __syncthreads();
  for (int e = 0; e < 64; e++) {
    int i = base + e;
    if (i < N) {
      unsigned u = src[i];
      unsigned d = (u >> shift) & 255u;
      unsigned c = hist[d][tid]++;
      dst[gbase[d] + c] = u;
    }
  }
}

// ---------------- per-voxel outputs ----------------
__global__ __launch_bounds__(256) void voxel_out_k(
    const unsigned* __restrict__ E, const unsigned* __restrict__ F,
    const unsigned* __restrict__ G, const unsigned* __restrict__ B,
    const float* __restrict__ C, const float4* __restrict__ bxyz,
    const float* __restrict__ feat, const float* __restrict__ vs,
    const unsigned* __restrict__ S,
    float* __restrict__ out0, float* __restrict__ out1, float* __restrict__ out2,
    float* __restrict__ out3, float* __restrict__ out4, float* __restrict__ out5,
    float* __restrict__ out6, float* __restrict__ out7, int V) {
  int i = blockIdx.x*256 + threadIdx.x;
  if (i >= V) return;
  unsigned deg = E[i];
  unsigned fin = F[i];
  unsigned off = fin - deg;
  unsigned p0 = G[off];
  unsigned code = B[p0];
  const int* Si = (const int*)S;
  unsigned d1 = (unsigned)Si[15], d2 = (unsigned)Si[16], d3 = (unsigned)Si[17];
  unsigned c3 = code % d3; unsigned r = code / d3;
  unsigned c2 = r % d2; r /= d2;
  unsigned c1 = r % d1; unsigned c0 = r / d1;
  float sb0=0.f, sb1=0.f, sb2=0.f, sb3=0.f;
  float sf[32];
  #pragma unroll
  for (int j = 0; j < 32; j++) sf[j] = 0.f;
  for (unsigned k = 0; k < deg; k++) {
    unsigned p = G[off + k];
    float4 pb = bxyz[p];
    sb0 += pb.x; sb1 += pb.y; sb2 += pb.z; sb3 += pb.w;
    const float4* fr = (const float4*)(feat + (size_t)p * 32);
    #pragma unroll
    for (int j = 0; j < 8; j++) {
      float4 fv = fr[j];
      sf[4*j+0] += fv.x; sf[4*j+1] += fv.y; sf[4*j+2] += fv.z; sf[4*j+3] += fv.w;
    }
  }
  float fd = (float)deg;
  float mb0 = sb0/fd, mb1 = sb1/fd, mb2 = sb2/fd, mb3 = sb3/fd;
  float pm1 = __uint_as_float(S[19]), pm2 = __uint_as_float(S[20]), pm3 = __uint_as_float(S[21]);
  float v1 = vs[1], v2 = vs[2], v3 = vs[3];
  float ct1 = __fadd_rn(__fadd_rn(__fmul_rn((float)c1, v1), pm1), 0.5f*v1);
  float ct2 = __fadd_rn(__fadd_rn(__fmul_rn((float)c2, v2), pm2), 0.5f*v2);
  float ct3 = __fadd_rn(__fadd_rn(__fmul_rn((float)c3, v3), pm3), 0.5f*v3);
  out0[i] = rintf(mb0);
  out1[3*i+0] = mb1; out1[3*i+1] = mb2; out1[3*i+2] = mb3;
  out2[3*i+0] = ct1; out2[3*i+1] = ct2; out2[3*i+2] = ct3;
  out3[4*i+0] = mb0; out3[4*i+1] = ct1; out3[4*i+2] = ct2; out3[4*i+3] = ct3;
  out4[4*i+0] = (float)c0; out4[4*i+1] = (float)c1; out4[4*i+2] = (float)c2; out4[4*i+3] = (float)c3;
  out5[4*i+0] = mb0; out5[4*i+1] = mb1; out5[4*i+2] = mb2; out5[4*i+3] = mb3;
  #pragma unroll
  for (int j = 0; j < 32; j++) out6[32*i+j] = sf[j] / fd;
  float hmax = __uint_as_float(S[23]);
  out7[i] = __fsub_rn(C[off + deg/2u], __fmul_rn((float)i, hmax));
}

extern "C" void kernel_launch(void* const* d_in, const int* in_sizes, int n_in,
                              void* d_out, int out_size, void* d_ws, size_t ws_size,
                              hipStream_t stream) {
  const float* bxyz = (const float*)d_in[0];
  const float* feat = (const float*)d_in[1];
  const float* h    = (const float*)d_in[2];
  const float* vs   = (const float*)d_in[3];
  int N = in_sizes[0] / 4;
  long V = ((long)out_size - 5L*(long)N) / 52L;

  float* out = (float*)d_out;
  float* out0 = out;
  float* out1 = out + V;
  float* out2 = out + 4*V;
  float* out3 = out + 7*V;
  float* out4 = out + 11*V;
  float* out5 = out + 15*V;
  float* out6 = out + 19*V;
  float* out7 = out + 51*V;
  float* out8 = out + 52*V;
  float* out9 = out + 52*V + N;

  // workspace carve (~58 MB)
  const long CAP = 40000000L;            // max possible code value +margin
  const int NW = (int)(CAP / 32);        // bitmap words = 1,250,000
  char* w = (char*)d_ws;
  size_t off = 0;
  auto alloc = [&](size_t bytes) -> void* {
    void* p = w + off;
    off += (bytes + 255) & ~(size_t)255;
    return p;
  };
  unsigned* S     = (unsigned*)alloc(1024);
  unsigned* Abits = (unsigned*)alloc((size_t)NW*4);
  unsigned* P     = (unsigned*)alloc((size_t)NW*4);
  unsigned* B     = (unsigned*)alloc((size_t)N*4);
  float*    C     = (float*)   alloc((size_t)N*4);
  unsigned* D     = (unsigned*)alloc((size_t)N*4);
  unsigned* E     = (unsigned*)alloc((size_t)V*4);
  unsigned* F     = (unsigned*)alloc((size_t)V*4);
  unsigned* G     = (unsigned*)alloc((size_t)N*4);
  int RNB = (N + 4095) / 4096;
  unsigned* H     = (unsigned*)alloc((size_t)256*RNB*4);
  unsigned* I     = (unsigned*)alloc((size_t)16384*4);
  (void)ws_size; (void)n_in;

  auto scan = [&](unsigned* src, unsigned* dst, long L) {
    int nb = (int)((L + 4095) / 4096);
    scan_partials_k<<<nb, 256, 0, stream>>>(src, I, L);
    scan_single_k<<<1, 256, 0, stream>>>(I, nb);
    scan_apply_k<<<nb, 256, 0, stream>>>(src, dst, I, L);
  };

  hipMemsetAsync(Abits, 0, (size_t)NW*4, stream);
  hipMemsetAsync(E, 0, (size_t)V*4, stream);
  init_scalars_k<<<1, 64, 0, stream>>>(S);
  reduce_stats_k<<<1024, 256, 0, stream>>>((const float4*)bxyz, h, N, S);
  finalize1_k<<<1, 64, 0, stream>>>(S);
  vc_minmax_k<<<1024, 256, 0, stream>>>((const float4*)bxyz, vs, S, N);
  finalize2_k<<<1, 64, 0, stream>>>(S);

  int gN = (N + 255) / 256;
  compute_codes_k<<<gN, 256, 0, stream>>>((const float4*)bxyz, vs, S, B, Abits,
                                          (float4*)out9, N, NW);
  popc_k<<<(NW + 255) / 256, 256, 0, stream>>>(Abits, P, NW);
  scan(P, P, (long)NW);                          // P = exclusive popcount prefix (rank base)

  point_rank_k<<<gN, 256, 0, stream>>>(B, Abits, P, h, S, out8, D, E, C, N);
  scan(E, F, V);                                 // F = exclusive offsets
  build_plist_k<<<gN, 256, 0, stream>>>(D, F, G, N);  // F becomes offset+deg

  unsigned* ps = (unsigned*)C;
  unsigned* pd = D;
  for (int pass = 0; pass < 4; pass++) {
    radix_hist_k<<<RNB, 64, 0, stream>>>(ps, H, N, pass*8);
    scan(H, H, (long)256*RNB);
    radix_scatter_k<<<RNB, 64, 0, stream>>>(ps, pd, H, N, pass*8);
    unsigned* t = ps; ps = pd; pd = t;
  }
  // after 4 passes sorted keys are back in C

  int gV = (int)((V + 255) / 256);
  voxel_out_k<<<gV, 256, 0, stream>>>(E, F, G, B, (const float*)C, (const float4*)bxyz,
                                      feat, vs, S, out0, out1, out2, out3, out4, out5,
                                      out6, out7, (int)V);
}

// Round 2
// 1335.784 us; speedup vs baseline: 1.5679x; 1.5679x over previous
//
#include <hip/hip_runtime.h>
#include <cstdint>
#include <cstddef>

#define FLT_MAX_ 3.402823466e+38f

// Scalar block S (u32 word indices in ws):
// 6..9 vcmin(int, ==0)  14..17 dims(int)
// 18..21 pcmin(float bits) 22 hmin(float bits) 23 hmax(float bits)

// ---------------- stats: two-stage, no global atomics ----------------
__global__ __launch_bounds__(256) void reduce_stats_k(const float4* __restrict__ bxyz,
    const float* __restrict__ h, int N, float* __restrict__ partial) {
  float mn0=FLT_MAX_, mn1=FLT_MAX_, mn2=FLT_MAX_, mn3=FLT_MAX_;
  float mx0=-FLT_MAX_, mx1=-FLT_MAX_, mx2=-FLT_MAX_, mx3=-FLT_MAX_;
  float hmn=FLT_MAX_, hmx=-FLT_MAX_;
  for (int i = blockIdx.x*blockDim.x + threadIdx.x; i < N; i += gridDim.x*blockDim.x) {
    float4 p = bxyz[i];
    mn0 = fminf(mn0, p.x); mn1 = fminf(mn1, p.y);
    mn2 = fminf(mn2, p.z); mn3 = fminf(mn3, p.w);
    mx0 = fmaxf(mx0, p.x); mx1 = fmaxf(mx1, p.y);
    mx2 = fmaxf(mx2, p.z); mx3 = fmaxf(mx3, p.w);
    float hv = h[i];
    hmn = fminf(hmn, hv); hmx = fmaxf(hmx, hv);
  }
  #pragma unroll
  for (int o = 32; o >= 1; o >>= 1) {
    mn0 = fminf(mn0, __shfl_down(mn0, o)); mx0 = fmaxf(mx0, __shfl_down(mx0, o));
    mn1 = fminf(mn1, __shfl_down(mn1, o)); mx1 = fmaxf(mx1, __shfl_down(mx1, o));
    mn2 = fminf(mn2, __shfl_down(mn2, o)); mx2 = fmaxf(mx2, __shfl_down(mx2, o));
    mn3 = fminf(mn3, __shfl_down(mn3, o)); mx3 = fmaxf(mx3, __shfl_down(mx3, o));
    hmn = fminf(hmn, __shfl_down(hmn, o)); hmx = fmaxf(hmx, __shfl_down(hmx, o));
  }
  __shared__ float red[4][10];
  int w = threadIdx.x >> 6;
  if ((threadIdx.x & 63) == 0) {
    red[w][0]=mn0; red[w][1]=mn1; red[w][2]=mn2; red[w][3]=mn3;
    red[w][4]=mx0; red[w][5]=mx1; red[w][6]=mx2; red[w][7]=mx3;
    red[w][8]=hmn; red[w][9]=hmx;
  }
  __syncthreads();
  if (threadIdx.x == 0) {
    float o_[10];
    #pragma unroll
    for (int j = 0; j < 10; j++) o_[j] = red[0][j];
    #pragma unroll
    for (int k = 1; k < 4; k++) {
      #pragma unroll
      for (int j = 0; j < 4; j++) o_[j] = fminf(o_[j], red[k][j]);
      #pragma unroll
      for (int j = 4; j < 8; j++) o_[j] = fmaxf(o_[j], red[k][j]);
      o_[8] = fminf(o_[8], red[k][8]);
      o_[9] = fmaxf(o_[9], red[k][9]);
    }
    #pragma unroll
    for (int j = 0; j < 10; j++) partial[blockIdx.x*10 + j] = o_[j];
  }
}

__global__ __launch_bounds__(256) void reduce_stats_final_k(const float* __restrict__ partial,
    int nb, const float* __restrict__ vs, unsigned* __restrict__ S) {
  float mn0=FLT_MAX_, mn1=FLT_MAX_, mn2=FLT_MAX_, mn3=FLT_MAX_;
  float mx0=-FLT_MAX_, mx1=-FLT_MAX_, mx2=-FLT_MAX_, mx3=-FLT_MAX_;
  float hmn=FLT_MAX_, hmx=-FLT_MAX_;
  for (int b = threadIdx.x; b < nb; b += 256) {
    const float* p = partial + b*10;
    mn0 = fminf(mn0, p[0]); mn1 = fminf(mn1, p[1]);
    mn2 = fminf(mn2, p[2]); mn3 = fminf(mn3, p[3]);
    mx0 = fmaxf(mx0, p[4]); mx1 = fmaxf(mx1, p[5]);
    mx2 = fmaxf(mx2, p[6]); mx3 = fmaxf(mx3, p[7]);
    hmn = fminf(hmn, p[8]); hmx = fmaxf(hmx, p[9]);
  }
  #pragma unroll
  for (int o = 32; o >= 1; o >>= 1) {
    mn0 = fminf(mn0, __shfl_down(mn0, o)); mx0 = fmaxf(mx0, __shfl_down(mx0, o));
    mn1 = fminf(mn1, __shfl_down(mn1, o)); mx1 = fmaxf(mx1, __shfl_down(mx1, o));
    mn2 = fminf(mn2, __shfl_down(mn2, o)); mx2 = fmaxf(mx2, __shfl_down(mx2, o));
    mn3 = fminf(mn3, __shfl_down(mn3, o)); mx3 = fmaxf(mx3, __shfl_down(mx3, o));
    hmn = fminf(hmn, __shfl_down(hmn, o)); hmx = fmaxf(hmx, __shfl_down(hmx, o));
  }
  __shared__ float red[4][10];
  int w = threadIdx.x >> 6;
  if ((threadIdx.x & 63) == 0) {
    red[w][0]=mn0; red[w][1]=mn1; red[w][2]=mn2; red[w][3]=mn3;
    red[w][4]=mx0; red[w][5]=mx1; red[w][6]=mx2; red[w][7]=mx3;
    red[w][8]=hmn; red[w][9]=hmx;
  }
  __syncthreads();
  if (threadIdx.x == 0) {
    float o_[10];
    #pragma unroll
    for (int j = 0; j < 10; j++) o_[j] = red[0][j];
    #pragma unroll
    for (int k = 1; k < 4; k++) {
      #pragma unroll
      for (int j = 0; j < 4; j++) o_[j] = fminf(o_[j], red[k][j]);
      #pragma unroll
      for (int j = 4; j < 8; j++) o_[j] = fmaxf(o_[j], red[k][j]);
      o_[8] = fminf(o_[8], red[k][8]);
      o_[9] = fmaxf(o_[9], red[k][9]);
    }
    int* Si = (int*)S;
    // pcmin / hmin / hmax bits
    S[18] = __float_as_uint(o_[0]); S[19] = __float_as_uint(o_[1]);
    S[20] = __float_as_uint(o_[2]); S[21] = __float_as_uint(o_[3]);
    S[22] = __float_as_uint(o_[8]); S[23] = __float_as_uint(o_[9]);
    // vcmin = floor((pcmin-pcmin)/vs) = 0 exactly (monotone ops)
    Si[6]=Si[7]=Si[8]=Si[9]=0;
    // dims[c] = floor((pcmax-pcmin)/vs) + 1 exactly (monotone ops attain max at pcmax)
    #pragma unroll
    for (int c = 0; c < 4; c++) {
      float vmaxc = (int)0; (void)vmaxc;
      float d = __fdiv_rn(__fsub_rn(o_[4+c], o_[c]), vs[c]);
      Si[14+c] = (int)floorf(d) + 1;
    }
  }
}

// ---------------- codes + bitmap ----------------
__global__ __launch_bounds__(256) void compute_codes_k(const float4* __restrict__ bxyz,
    const float* __restrict__ vs, const unsigned* __restrict__ S,
    unsigned* __restrict__ B, unsigned* __restrict__ Abits, float4* __restrict__ out9,
    int N, int NW) {
  int i = blockIdx.x*256 + threadIdx.x;
  if (i >= N) return;
  const int* Si = (const int*)S;
  float pm0 = __uint_as_float(S[18]), pm1 = __uint_as_float(S[19]);
  float pm2 = __uint_as_float(S[20]), pm3 = __uint_as_float(S[21]);
  float v0 = vs[0], v1 = vs[1], v2 = vs[2], v3 = vs[3];
  float4 p = bxyz[i];
  int c0 = (int)floorf(__fdiv_rn(__fsub_rn(p.x, pm0), v0));
  int c1 = (int)floorf(__fdiv_rn(__fsub_rn(p.y, pm1), v1));
  int c2 = (int)floorf(__fdiv_rn(__fsub_rn(p.z, pm2), v2));
  int c3 = (int)floorf(__fdiv_rn(__fsub_rn(p.w, pm3), v3));
  int d1 = Si[15], d2 = Si[16], d3 = Si[17];
  unsigned code = (unsigned)(((c0*d1 + c1)*d2 + c2)*d3 + c3);
  B[i] = code;
  unsigned wi = code >> 5;
  if ((int)wi < NW) atomicOr(&Abits[wi], 1u << (code & 31u));
  out9[i] = make_float4((float)c0, (float)c1, (float)c2, (float)c3);
}

__global__ __launch_bounds__(256) void popc_k(const unsigned* __restrict__ Abits,
    unsigned* __restrict__ P, int NW) {
  int i = blockIdx.x*256 + threadIdx.x;
  if (i < NW) P[i] = (unsigned)__popc(Abits[i]);
}

// ---------------- generic u32 exclusive scan (3-kernel) ----------------
__device__ __forceinline__ unsigned wave_incl_scan_u32(unsigned x) {
  int lane = threadIdx.x & 63;
  #pragma unroll
  for (int d = 1; d < 64; d <<= 1) {
    unsigned y = __shfl_up(x, d);
    if (lane >= d) x += y;
  }
  return x;
}

__device__ __forceinline__ unsigned block_excl_scan256(unsigned s, unsigned* lds5) {
  int lane = threadIdx.x & 63, w = threadIdx.x >> 6;
  unsigned incl = wave_incl_scan_u32(s);
  if (lane == 63) lds5[w] = incl;
  __syncthreads();
  if (threadIdx.x == 0) {
    unsigned run = 0;
    #pragma unroll
    for (int k = 0; k < 4; k++) { unsigned t = lds5[k]; lds5[k] = run; run += t; }
    lds5[4] = run;
  }
  __syncthreads();
  return lds5[w] + (incl - s);
}

__global__ __launch_bounds__(256) void scan_partials_k(const unsigned* __restrict__ src,
    unsigned* __restrict__ partial, long L) {
  __shared__ unsigned lds5[5];
  long base = (long)blockIdx.x*4096 + (long)threadIdx.x*16;
  unsigned s = 0;
  #pragma unroll
  for (int k = 0; k < 16; k++) { long i = base + k; if (i < L) s += src[i]; }
  block_excl_scan256(s, lds5);
  if (threadIdx.x == 0) partial[blockIdx.x] = lds5[4];
}

__global__ __launch_bounds__(256) void scan_single_k(unsigned* arr, int L) {
  __shared__ unsigned lds5[5];
  __shared__ unsigned carry_s;
  if (threadIdx.x == 0) carry_s = 0;
  __syncthreads();
  int tiles = (L + 4095) / 4096;
  for (int t = 0; t < tiles; t++) {
    long base = (long)t*4096 + (long)threadIdx.x*16;
    unsigned v[16], s = 0;
    #pragma unroll
    for (int k = 0; k < 16; k++) { long i = base + k; v[k] = (i < L) ? arr[i] : 0u; s += v[k]; }
    unsigned carry = carry_s;
    unsigned e = block_excl_scan256(s, lds5);
    unsigned run = carry + e;
    #pragma unroll
    for (int k = 0; k < 16; k++) { long i = base + k; if (i < L) arr[i] = run; run += v[k]; }
    __syncthreads();
    if (threadIdx.x == 0) carry_s = carry + lds5[4];
    __syncthreads();
  }
}

__global__ __launch_bounds__(256) void scan_apply_k(const unsigned* __restrict__ src,
    unsigned* __restrict__ dst, const unsigned* __restrict__ partial, long L) {
  __shared__ unsigned lds5[5];
  long base = (long)blockIdx.x*4096 + (long)threadIdx.x*16;
  unsigned v[16], s = 0;
  #pragma unroll
  for (int k = 0; k < 16; k++) { long i = base + k; v[k] = (i < L) ? src[i] : 0u; s += v[k]; }
  unsigned e = block_excl_scan256(s, lds5);
  unsigned run = partial[blockIdx.x] + e;
  #pragma unroll
  for (int k = 0; k < 16; k++) { long i = base + k; if (i < L) dst[i] = run; run += v[k]; }
}

// ---------------- per-point rank / tval / counts ----------------
__global__ __launch_bounds__(256) void point_rank_k(const unsigned* __restrict__ B,
    const unsigned* __restrict__ Abits, const unsigned* __restrict__ P,
    const float* __restrict__ h, const unsigned* __restrict__ S,
    float* __restrict__ out8, unsigned* __restrict__ D, unsigned* __restrict__ E,
    float* __restrict__ C, int N) {
  int i = blockIdx.x*256 + threadIdx.x;
  if (i >= N) return;
  unsigned code = B[i];
  unsigned wi = code >> 5, bi = code & 31u;
  unsigned idx = P[wi] + (unsigned)__popc(Abits[wi] & ((1u << bi) - 1u));
  out8[i] = (float)idx;
  D[i] = idx;
  atomicAdd(&E[idx], 1u);
  float hmin = __uint_as_float(S[22]);
  float hmax = __uint_as_float(S[23]);
  C[i] = __fadd_rn(__fsub_rn(h[i], hmin), __fmul_rn((float)idx, hmax));
}

__global__ __launch_bounds__(256) void build_plist_k(const unsigned* __restrict__ D,
    unsigned* __restrict__ F, unsigned* __restrict__ G, int N) {
  int i = blockIdx.x*256 + threadIdx.x;
  if (i >= N) return;
  unsigned idx = D[i];
  unsigned pos = atomicAdd(&F[idx], 1u);
  G[pos] = (unsigned)i;
}

// ---------------- stable LSD radix sort, 4 x 8-bit, keys-only ----------------
// 256 threads/block, 16 elems/thread, tile=4096. Stable order = (k, wave, lane).
__global__ __launch_bounds__(256) void radix_hist_k(const unsigned* __restrict__ src,
    unsigned* __restrict__ ghist, int N, int shift, int nb) {
  __shared__ unsigned hist[256];
  int t = threadIdx.x;
  hist[t] = 0u;
  __syncthreads();
  int base = blockIdx.x*4096;
  #pragma unroll
  for (int k = 0; k < 16; k++) {
    int i = base + k*256 + t;
    if (i < N) atomicAdd(&hist[(src[i] >> shift) & 255u], 1u);
  }
  __syncthreads();
  ghist[t*nb + blockIdx.x] = hist[t];
}

__global__ __launch_bounds__(256) void radix_scatter_k(const unsigned* __restrict__ src,
    unsigned* __restrict__ dst, const unsigned* __restrict__ ghist,
    int N, int shift, int nb) {
  __shared__ unsigned short hist[256][66];   // [digit][subgroup(k*4+wave)], +2 pad
  __shared__ unsigned gbase[256];
  int t = threadIdx.x;
  int lane = t & 63, wave = t >> 6;
  unsigned* hz = (unsigned*)&hist[0][0];
  for (int k = t; k < 256*33; k += 256) hz[k] = 0u;
  gbase[t] = ghist[t*nb + blockIdx.x];
  __syncthreads();
  unsigned key[16], meta[16];
  int base = blockIdx.x*4096;
  unsigned long long lower = (lane == 0) ? 0ull : (~0ull >> (64 - lane));
  #pragma unroll
  for (int k = 0; k < 16; k++) {
    int i = base + k*256 + t;
    bool valid = (i < N);
    unsigned u = valid ? src[i] : 0u;
    unsigned d = (u >> shift) & 255u;
    unsigned long long m = __ballot(valid ? 1 : 0);
    #pragma unroll
    for (int b = 0; b < 8; b++) {
      unsigned long long bb = __ballot((int)((d >> b) & 1u));
      m &= ((d >> b) & 1u) ? bb : ~bb;
    }
    key[k] = u;
    unsigned subrank = (unsigned)__popcll(m & lower);
    meta[k] = valid ? ((subrank << 8) | d) : 0xFFFFFFFFu;
    if (valid && subrank == 0u) {
      hist[d][k*4 + wave] = (unsigned short)__popcll(m);
    }
  }
  __syncthreads();
  {
    unsigned run = 0;
    #pragma unroll
    for (int s = 0; s < 64; s++) {
      unsigned c = hist[t][s];
      hist[t][s] = (unsigned short)run;
      run += c;
    }
  }
  __syncthreads();
  #pragma unroll
  for (int k = 0; k < 16; k++) {
    unsigned mt = meta[k];
    if (mt != 0xFFFFFFFFu) {
      unsigned d = mt & 255u, sr = mt >> 8;
      unsigned pos = gbase[d] + (unsigned)hist[d][k*4 + wave] + sr;
      dst[pos] = key[k];
    }
  }
}

// ---------------- per-voxel outputs ----------------
__global__ __launch_bounds__(256) void voxel_out_k(
    const unsigned* __restrict__ E, const unsigned* __restrict__ F,
    const unsigned* __restrict__ G, const unsigned* __restrict__ B,
    const float* __restrict__ C, const float4* __restrict__ bxyz,
    const float* __restrict__ feat, const float* __restrict__ vs,
    const unsigned* __restrict__ S,
    float* __restrict__ out0, float* __restrict__ out1, float* __restrict__ out2,
    float* __restrict__ out3, float* __restrict__ out4, float* __restrict__ out5,
    float* __restrict__ out6, float* __restrict__ out7, int V) {
  int i = blockIdx.x*256 + threadIdx.x;
  if (i >= V) return;
  unsigned deg = E[i];
  unsigned fin = F[i];
  unsigned off = fin - deg;
  unsigned p0 = G[off];
  unsigned code = B[p0];
  const int* Si = (const int*)S;
  unsigned d1 = (unsigned)Si[15], d2 = (unsigned)Si[16], d3 = (unsigned)Si[17];
  unsigned c3 = code % d3; unsigned r = code / d3;
  unsigned c2 = r % d2; r /= d2;
  unsigned c1 = r % d1; unsigned c0 = r / d1;
  float sb0=0.f, sb1=0.f, sb2=0.f, sb3=0.f;
  float sf[32];
  #pragma unroll
  for (int j = 0; j < 32; j++) sf[j] = 0.f;
  for (unsigned k = 0; k < deg; k++) {
    unsigned p = G[off + k];
    float4 pb = bxyz[p];
    sb0 += pb.x; sb1 += pb.y; sb2 += pb.z; sb3 += pb.w;
    const float4* fr = (const float4*)(feat + (size_t)p * 32);
    #pragma unroll
    for (int j = 0; j < 8; j++) {
      float4 fv = fr[j];
      sf[4*j+0] += fv.x; sf[4*j+1] += fv.y; sf[4*j+2] += fv.z; sf[4*j+3] += fv.w;
    }
  }
  float fd = (float)deg;
  float mb0 = sb0/fd, mb1 = sb1/fd, mb2 = sb2/fd, mb3 = sb3/fd;
  float pm1 = __uint_as_float(S[19]), pm2 = __uint_as_float(S[20]), pm3 = __uint_as_float(S[21]);
  float v1 = vs[1], v2 = vs[2], v3 = vs[3];
  float ct1 = __fadd_rn(__fadd_rn(__fmul_rn((float)c1, v1), pm1), 0.5f*v1);
  float ct2 = __fadd_rn(__fadd_rn(__fmul_rn((float)c2, v2), pm2), 0.5f*v2);
  float ct3 = __fadd_rn(__fadd_rn(__fmul_rn((float)c3, v3), pm3), 0.5f*v3);
  out0[i] = rintf(mb0);
  out1[3*i+0] = mb1; out1[3*i+1] = mb2; out1[3*i+2] = mb3;
  out2[3*i+0] = ct1; out2[3*i+1] = ct2; out2[3*i+2] = ct3;
  out3[4*i+0] = mb0; out3[4*i+1] = ct1; out3[4*i+2] = ct2; out3[4*i+3] = ct3;
  out4[4*i+0] = (float)c0; out4[4*i+1] = (float)c1; out4[4*i+2] = (float)c2; out4[4*i+3] = (float)c3;
  out5[4*i+0] = mb0; out5[4*i+1] = mb1; out5[4*i+2] = mb2; out5[4*i+3] = mb3;
  #pragma unroll
  for (int j = 0; j < 32; j++) out6[32*i+j] = sf[j] / fd;
  float hmax = __uint_as_float(S[23]);
  out7[i] = __fsub_rn(C[off + deg/2u], __fmul_rn((float)i, hmax));
}

extern "C" void kernel_launch(void* const* d_in, const int* in_sizes, int n_in,
                              void* d_out, int out_size, void* d_ws, size_t ws_size,
                              hipStream_t stream) {
  const float* bxyz = (const float*)d_in[0];
  const float* feat = (const float*)d_in[1];
  const float* h    = (const float*)d_in[2];
  const float* vs   = (const float*)d_in[3];
  int N = in_sizes[0] / 4;
  long V = ((long)out_size - 5L*(long)N) / 52L;

  float* out = (float*)d_out;
  float* out0 = out;
  float* out1 = out + V;
  float* out2 = out + 4*V;
  float* out3 = out + 7*V;
  float* out4 = out + 11*V;
  float* out5 = out + 15*V;
  float* out6 = out + 19*V;
  float* out7 = out + 51*V;
  float* out8 = out + 52*V;
  float* out9 = out + 52*V + N;

  const long CAP = 40000000L;
  const int NW = (int)(CAP / 32);
  char* w = (char*)d_ws;
  size_t off = 0;
  auto alloc = [&](size_t bytes) -> void* {
    void* p = w + off;
    off += (bytes + 255) & ~(size_t)255;
    return p;
  };
  unsigned* S     = (unsigned*)alloc(1024);
  unsigned* Abits = (unsigned*)alloc((size_t)NW*4);
  unsigned* P     = (unsigned*)alloc((size_t)NW*4);
  unsigned* B     = (unsigned*)alloc((size_t)N*4);
  float*    C     = (float*)   alloc((size_t)N*4);
  unsigned* D     = (unsigned*)alloc((size_t)N*4);
  unsigned* E     = (unsigned*)alloc((size_t)V*4);
  unsigned* F     = (unsigned*)alloc((size_t)V*4);
  unsigned* G     = (unsigned*)alloc((size_t)N*4);
  int RNB = (N + 4095) / 4096;
  unsigned* H     = (unsigned*)alloc((size_t)256*RNB*4);
  unsigned* I     = (unsigned*)alloc((size_t)16384*4);
  float*    SP    = (float*)   alloc((size_t)512*10*4);
  (void)ws_size; (void)n_in;

  auto scan = [&](unsigned* src, unsigned* dst, long L) {
    int nb = (int)((L + 4095) / 4096);
    scan_partials_k<<<nb, 256, 0, stream>>>(src, I, L);
    scan_single_k<<<1, 256, 0, stream>>>(I, nb);
    scan_apply_k<<<nb, 256, 0, stream>>>(src, dst, I, L);
  };

  hipMemsetAsync(Abits, 0, (size_t)NW*4, stream);
  hipMemsetAsync(E, 0, (size_t)V*4, stream);

  const int SB = 512;
  reduce_stats_k<<<SB, 256, 0, stream>>>((const float4*)bxyz, h, N, SP);
  reduce_stats_final_k<<<1, 256, 0, stream>>>(SP, SB, vs, S);

  int gN = (N + 255) / 256;
  compute_codes_k<<<gN, 256, 0, stream>>>((const float4*)bxyz, vs, S, B, Abits,
                                          (float4*)out9, N, NW);
  popc_k<<<(NW + 255) / 256, 256, 0, stream>>>(Abits, P, NW);
  scan(P, P, (long)NW);

  point_rank_k<<<gN, 256, 0, stream>>>(B, Abits, P, h, S, out8, D, E, C, N);
  scan(E, F, V);
  build_plist_k<<<gN, 256, 0, stream>>>(D, F, G, N);

  unsigned* ps = (unsigned*)C;
  unsigned* pd = D;
  for (int pass = 0; pass < 4; pass++) {
    radix_hist_k<<<RNB, 256, 0, stream>>>(ps, H, N, pass*8, RNB);
    scan(H, H, (long)256*RNB);
    radix_scatter_k<<<RNB, 256, 0, stream>>>(ps, pd, H, N, pass*8, RNB);
    unsigned* t = ps; ps = pd; pd = t;
  }

  int gV = (int)((V + 255) / 256);
  voxel_out_k<<<gV, 256, 0, stream>>>(E, F, G, B, (const float*)C, (const float4*)bxyz,
                                      feat, vs, S, out0, out1, out2, out3, out4, out5,
                                      out6, out7, (int)V);
}